// Round 10
// baseline (4277.178 us; speedup 1.0000x reference)
//
#include <hip/hip_runtime.h>
#include <hip/hip_bf16.h>

// ConvLSTM (2 layers) on MI355X. Merged packed tensor P (B,64,64,288) bf16:
//   hi: [x(1), h0(128), h1(12), pad(3)]  lo: [h0_lo(128), pad(16)]
// R10 = R9 resubmit (container infra failure, no kernel verdict; precedent:
// R4->R5 and R7->R8 identical resubmits both ran fine).
// R9: R6 geometry (256-thr blocks, wave tile 64x64, acc 4x4, LDS 33792) with
//  - B-weight prefetch in 3-tap groups (12-load batches, parity double buffer)
//  - layer1 (step t-1) blocks interleaved at bx%5==4 (2560-block fused grid)
//  - nt-adjacent block swizzle (idx&3) for P-halo L2/L3 reuse.
// Race-free fusion: layer0 writes Pnext ch{0-128,144-271}, layer1 writes ch{129-140};
// layer1's weights are zero on channels it ignores.

typedef __attribute__((ext_vector_type(8))) short short8;
typedef __attribute__((ext_vector_type(4))) float float4v;

#define CS 288
#define KTOT 2592         // 9*288

__device__ __forceinline__ float sigf(float x) { return 1.f / (1.f + __expf(-x)); }
__device__ __forceinline__ short f2bs(float v) {
  __hip_bfloat16 h = __float2bfloat16(v);
  return *(short*)&h;
}
__device__ __forceinline__ float bs2f(short s) {
  __hip_bfloat16 h; *(short*)&h = s; return __bfloat162float(h);
}

__device__ __forceinline__ void async_ld16(const short* g, short* l) {
  __builtin_amdgcn_global_load_lds(
      (const __attribute__((address_space(1))) unsigned int*)g,
      (__attribute__((address_space(3))) unsigned int*)l, 16, 0, 0);
}

// Stage one halo row (66 px x 32 ch) into LDS at dstRow (row-major, 32ch/px).
__device__ __forceinline__ void stage_row(const short* __restrict__ rowPtr, bool rowOK,
                                          short* dstRow, int lane,
                                          const short* __restrict__ zp) {
  #pragma unroll
  for (int j = 0; j < 4; ++j) {
    int e = j * 64 + lane;
    int px = e >> 2, v = e & 3;
    int xx = px - 1;
    const short* g = (rowOK && xx >= 0) ? (rowPtr + (size_t)xx * CS + v * 8) : zp;
    async_ld16(g, dstRow + e * 8);
  }
  if (lane < 8) {
    int px = 64 + (lane >> 2), v = lane & 3, xx = px - 1;
    short8 val = {0, 0, 0, 0, 0, 0, 0, 0};
    if (rowOK && xx < 64) val = *(const short8*)(rowPtr + (size_t)xx * CS + v * 8);
    *(short8*)(dstRow + px * 32 + v * 8) = val;
  }
}

// ---- dtype detect ----
__global__ void detect_dtype(const unsigned short* __restrict__ w0, int* __restrict__ flag) {
  int lane = threadIdx.x;
  int cnt = 0;
  for (int i = 0; i < 4; ++i) {
    unsigned short u = w0[2 * (lane + 64 * i)];
    int e = (u >> 7) & 0xFF;
    unsigned long long b = __ballot(e >= 0xC0);
    cnt += __popcll(b);
  }
  if (lane == 0) *flag = (cnt > 32) ? 1 : 0;   // 1 = fp32 inputs
}

__global__ void canon_x(const void* __restrict__ hist, short* __restrict__ Xc,
                        const int* __restrict__ flag) {
  int i = blockIdx.x * 256 + threadIdx.x;      // < 786432
  float v = (*flag) ? ((const float*)hist)[i] : bs2f(((const short*)hist)[i]);
  if (!isfinite(v) || fabsf(v) > 1e4f) v = 0.f;
  Xc[i] = f2bs(v);
}

__global__ void canon_b(const void* __restrict__ b0, const void* __restrict__ b1,
                        float* __restrict__ Bc0, float* __restrict__ Bc1,
                        const int* __restrict__ flag) {
  int i = blockIdx.x * 256 + threadIdx.x;
  int fl = *flag;
  if (i < 512) {
    float v = fl ? ((const float*)b0)[i] : bs2f(((const short*)b0)[i]);
    if (!isfinite(v) || fabsf(v) > 1e4f) v = 0.f;
    Bc0[i] = v;
  } else if (i < 560) {
    int j = i - 512;
    float v = fl ? ((const float*)b1)[j] : bs2f(((const short*)b1)[j]);
    if (!isfinite(v) || fabsf(v) > 1e4f) v = 0.f;
    Bc1[j] = v;
  }
}

// layer0 W0 (512,129,3,3): P-ch 0=x, 1..128=h0 hi, 144..271=h0 lo.
__global__ void prep_w0(const void* __restrict__ W0, short* __restrict__ Wp,
                        const int* __restrict__ flag) {
  int i = blockIdx.x * 256 + threadIdx.x;
  if (i >= 512 * KTOT) return;
  int fl = *flag;
  int co = i / KTOT, k = i - co * KTOT;
  int tap = k / CS, c = k - tap * CS;
  int ci = -1;
  if (c == 0) ci = 0;
  else if (c <= 128) ci = c;
  else if (c >= 144 && c < 272) ci = c - 143;
  float w = 0.f;
  if (ci >= 0) {
    int widx = (co * 129 + ci) * 9 + tap;
    w = fl ? ((const float*)W0)[widx] : bs2f(((const short*)W0)[widx]);
    if (!isfinite(w) || fabsf(w) > 1e4f) w = 0.f;
  }
  Wp[i] = f2bs(w);
}

// layer1 W1 (48,140,3,3): P-ch 1..128=h0 hi, 129..140=h1, 144..271=h0 lo.
__global__ void prep_w1(const void* __restrict__ W1, short* __restrict__ Wp,
                        const int* __restrict__ flag) {
  int i = blockIdx.x * 256 + threadIdx.x;
  if (i >= 48 * KTOT) return;
  int fl = *flag;
  int co = i / KTOT, k = i - co * KTOT;
  int tap = k / CS, c = k - tap * CS;
  int ci = -1;
  if (c >= 1 && c <= 140) ci = c - 1;
  else if (c >= 144 && c < 272) ci = c - 144;
  float w = 0.f;
  if (ci >= 0) {
    int widx = (co * 140 + ci) * 9 + tap;
    w = fl ? ((const float*)W1)[widx] : bs2f(((const short*)W1)[widx]);
    if (!isfinite(w) || fabsf(w) > 1e4f) w = 0.f;
  }
  Wp[i] = f2bs(w);
}

__global__ void fill_x0(const short* __restrict__ Xc, short* __restrict__ P0) {
  int p = blockIdx.x * 256 + threadIdx.x;      // b*4096 + pix
  int b = p >> 12, pix = p & 4095;
  P0[(size_t)p * CS] = Xc[b * 12 * 4096 + pix];
}

// ---- fused step: bx%5!=4 -> layer0 step t (2048 blocks); bx%5==4 -> layer1 step t-1 (512) ----
__global__ __launch_bounds__(256, 2) void fused_step(
    const short* __restrict__ Pcur, short* __restrict__ Pnext,
    const short* __restrict__ Wp0, const float* __restrict__ Bc0,
    float* __restrict__ C0, const short* __restrict__ Xc,
    const short* __restrict__ Wp1, const float* __restrict__ Bc1,
    float* __restrict__ C1, void* __restrict__ outp,
    const short* __restrict__ zp, const int* __restrict__ flagp, int t) {
  __shared__ __align__(16) short halo[2 * 4 * 66 * 32];   // 33792 B dbuf

  int bx = blockIdx.x;
  int tid = threadIdx.x, wave = tid >> 6, lane = tid & 63;
  int ln15 = lane & 15, quad = lane >> 4;

  if ((bx % 5) != 4) {
    // ================= layer 0, step t =================
    if (t >= 12) return;
    int idx = bx - bx / 5;                     // 0..2047
    int nt = idx & 3, mt = idx >> 2;           // nt-siblings adjacent (L2/L3 reuse of P)
    int b = mt >> 5, y0 = (mt & 31) * 2;
    int wm = wave & 1, wn = wave >> 1;
    int hc = nt * 32 + wn * 16 + ln15;

    float4v acc[4][4];
    #pragma unroll
    for (int i = 0; i < 4; ++i)
      #pragma unroll
      for (int j = 0; j < 4; ++j) acc[i][j] = (float4v){0.f, 0.f, 0.f, 0.f};

    // B frag addr for (g, tap, c0): wbase + g*128*KTOT + tap*CS + c0
    const short* wbase = Wp0 + (size_t)hc * KTOT + quad * 8;

    // parity double-buffered 3-tap-group B registers: bb[par][ti*4+g]
    short8 bb[2][12];
    #pragma unroll
    for (int ti = 0; ti < 3; ++ti)
      #pragma unroll
      for (int g = 0; g < 4; ++g)
        bb[0][ti * 4 + g] = *(const short8*)(wbase + (size_t)g * 128 * KTOT + ti * CS);

    int yy = y0 - 1 + wave;
    bool rowOK = (yy >= 0) && (yy < 64);
    const short* rowBase = Pcur + (size_t)((b * 64 + yy) * 64) * CS;

    stage_row(rowBase, rowOK, halo + wave * 2112, lane, zp);
    __syncthreads();

    // flat loop over 27 (chunk, tap-group) pairs; fully unrolled (compile-time parity)
    #pragma unroll
    for (int gi = 0; gi < 27; ++gi) {
      const int ch = gi / 3, grp = gi % 3;     // grp == dy
      const int c0 = ch * 32;
      const int cur = gi & 1, nxt = cur ^ 1;
      const short* curh = halo + (ch & 1) * 8448;

      if (grp == 0 && ch < 8)
        stage_row(rowBase + c0 + 32, rowOK, halo + ((ch + 1) & 1) * 8448 + wave * 2112,
                  lane, zp);

      if (gi < 26) {                           // prefetch next group's 12 B frags
        const int ngi = gi + 1;
        const int nch = ngi / 3, ngrp = ngi % 3, nc0 = nch * 32;
        #pragma unroll
        for (int ti = 0; ti < 3; ++ti)
          #pragma unroll
          for (int g = 0; g < 4; ++g)
            bb[nxt][ti * 4 + g] = *(const short8*)(wbase + (size_t)g * 128 * KTOT
                                                   + (ngrp * 3 + ti) * CS + nc0);
      }

      #pragma unroll
      for (int ti = 0; ti < 3; ++ti) {         // tap = grp*3+ti -> dy=grp, dx=ti
        short8 af[4];
        #pragma unroll
        for (int mf = 0; mf < 4; ++mf)
          af[mf] = *(const short8*)&curh[((wm + grp) * 66 + mf * 16 + ln15 + ti) * 32 + quad * 8];
        #pragma unroll
        for (int g = 0; g < 4; ++g)
          #pragma unroll
          for (int mf = 0; mf < 4; ++mf)
            acc[mf][g] = __builtin_amdgcn_mfma_f32_16x16x32_bf16(af[mf], bb[cur][ti * 4 + g],
                                                                 acc[mf][g], 0, 0, 0);
      }
      if (grp == 2) __syncthreads();
    }

    // epilogue: all 4 gates in-register per (pix,hc)
    float bi = Bc0[hc], bff = Bc0[128 + hc], bo = Bc0[256 + hc], bg = Bc0[384 + hc];
    int rowPix = (b * 64 + y0 + wm) * 64;
    #pragma unroll
    for (int mf = 0; mf < 4; ++mf) {
      #pragma unroll
      for (int r = 0; r < 4; ++r) {
        int x = mf * 16 + quad * 4 + r;        // C/D row = quad*4 + reg
        int pix = rowPix + x;
        float zi = acc[mf][0][r] + bi;
        float zf = acc[mf][1][r] + bff;
        float zo = acc[mf][2][r] + bo;
        float zg = acc[mf][3][r] + bg;
        float cprev = C0[(size_t)pix * 128 + hc];
        float cn = sigf(zf) * cprev + sigf(zi) * tanhf(zg);
        float hn = sigf(zo) * tanhf(cn);
        C0[(size_t)pix * 128 + hc] = cn;
        short hi = f2bs(hn);
        short lo = f2bs(hn - bs2f(hi));
        Pnext[(size_t)pix * CS + 1 + hc] = hi;
        Pnext[(size_t)pix * CS + 144 + hc] = lo;
      }
    }
    if (nt == 0 && t < 11 && tid < 128) {
      int rr = tid >> 6, x = tid & 63;
      int yw = y0 + rr;
      Pnext[(size_t)((b * 64 + yw) * 64 + x) * CS] = Xc[(b * 12 + t + 1) * 4096 + yw * 64 + x];
    }
  } else {
    // ================= layer 1, step t-1 =================
    if (t < 1) return;
    int t1 = t - 1;
    int idx1 = bx / 5;                         // 0..511
    int b = idx1 >> 5, y0 = (idx1 & 31) * 2;
    int wr = wave >> 1, wh = wave & 1;
    int flagv = *flagp;

    float4v acc[2][3];
    #pragma unroll
    for (int i = 0; i < 2; ++i)
      #pragma unroll
      for (int j = 0; j < 3; ++j) acc[i][j] = (float4v){0.f, 0.f, 0.f, 0.f};

    int yy = y0 - 1 + wave;
    bool rowOK = (yy >= 0) && (yy < 64);
    const short* rowBase = Pcur + (size_t)((b * 64 + yy) * 64) * CS;

    const short* wbase = Wp1 + (size_t)ln15 * KTOT + quad * 8;
    short8 bcur[3], bnxt[3];
    #pragma unroll
    for (int nf = 0; nf < 3; ++nf)
      bcur[nf] = *(const short8*)(wbase + (size_t)nf * 16 * KTOT);

    stage_row(rowBase, rowOK, halo + wave * 2112, lane, zp);
    __syncthreads();

    for (int ch = 0; ch < 9; ++ch) {
      int c0 = ch * 32;
      const short* cur = halo + (ch & 1) * 8448;
      if (ch < 8)
        stage_row(rowBase + c0 + 32, rowOK, halo + ((ch + 1) & 1) * 8448 + wave * 2112,
                  lane, zp);
      #pragma unroll
      for (int tap = 0; tap < 9; ++tap) {
        int dy = tap / 3, dx = tap - dy * 3;
        int ntap = (tap < 8) ? tap + 1 : 0;
        int nc0 = (tap < 8) ? c0 : ((ch < 8) ? c0 + 32 : c0);
        #pragma unroll
        for (int nf = 0; nf < 3; ++nf)
          bnxt[nf] = *(const short8*)(wbase + (size_t)nf * 16 * KTOT + ntap * CS + nc0);

        short8 af[2];
        #pragma unroll
        for (int mf = 0; mf < 2; ++mf)
          af[mf] = *(const short8*)&cur[((wr + dy) * 66 + wh * 32 + mf * 16 + ln15 + dx) * 32
                                        + quad * 8];
        #pragma unroll
        for (int nf = 0; nf < 3; ++nf)
          #pragma unroll
          for (int mf = 0; mf < 2; ++mf)
            acc[mf][nf] = __builtin_amdgcn_mfma_f32_16x16x32_bf16(af[mf], bcur[nf], acc[mf][nf], 0, 0, 0);
        #pragma unroll
        for (int nf = 0; nf < 3; ++nf) bcur[nf] = bnxt[nf];
      }
      __syncthreads();
    }

    // z -> LDS (reuse halo: 128*48 fp32 = 24576 B), then gate pass
    float* zbuf = (float*)halo;
    #pragma unroll
    for (int mf = 0; mf < 2; ++mf)
      #pragma unroll
      for (int nf = 0; nf < 3; ++nf)
        #pragma unroll
        for (int r = 0; r < 4; ++r) {
          int pxl = wr * 64 + wh * 32 + mf * 16 + quad * 4 + r;
          zbuf[pxl * 48 + nf * 16 + ln15] = acc[mf][nf][r];
        }
    __syncthreads();

    #pragma unroll
    for (int k = 0; k < 6; ++k) {
      int id = k * 256 + tid;
      int hc = id >> 7, pxl = id & 127;
      float zi = zbuf[pxl * 48 + hc]      + Bc1[hc];
      float zf = zbuf[pxl * 48 + 12 + hc] + Bc1[12 + hc];
      float zo = zbuf[pxl * 48 + 24 + hc] + Bc1[24 + hc];
      float zg = zbuf[pxl * 48 + 36 + hc] + Bc1[36 + hc];
      int y = y0 + (pxl >> 6), x = pxl & 63;
      int pix = (b * 64 + y) * 64 + x;
      float cprev = C1[(size_t)pix * 12 + hc];
      float cn = sigf(zf) * cprev + sigf(zi) * tanhf(zg);
      float hn = sigf(zo) * tanhf(cn);
      C1[(size_t)pix * 12 + hc] = cn;
      Pnext[(size_t)pix * CS + 129 + hc] = f2bs(hn);
      if (t1 == 11) {
        int oidx = (b * 12 + hc) * 4096 + y * 64 + x;
        if (flagv) ((float*)outp)[oidx] = hn;
        else ((short*)outp)[oidx] = f2bs(hn);
      }
    }
  }
}

extern "C" void kernel_launch(void* const* d_in, const int* in_sizes, int n_in,
                              void* d_out, int out_size, void* d_ws, size_t ws_size,
                              hipStream_t stream) {
  const void* hist = d_in[0];                  // (16,12,4096,1)
  const void* W0 = d_in[2];                    // (512,129,3,3)
  const void* b0 = d_in[3];
  const void* W1 = d_in[4];                    // (48,140,3,3)
  const void* b1 = d_in[5];

  char* ws = (char*)d_ws;
  const size_t PszB = (size_t)16 * 4096 * CS * 2;     // 37,748,736
  short* P[2] = {(short*)ws, (short*)(ws + PszB)};
  float* C0 = (float*)(ws + 2 * PszB);                // 33,554,432
  const size_t C0e = 2 * PszB + 33554432;
  float* C1 = (float*)(ws + C0e);                     // 3,145,728
  const size_t C1e = C0e + 3145728;
  short* zp = (short*)(ws + C1e);                     // 256 B zero page
  const size_t zpe = C1e + 256;
  short* Xc = (short*)(ws + zpe);                     // 1,572,864
  const size_t Xce = zpe + 1572864;
  short* Wp0 = (short*)(ws + Xce);                    // 2,654,208
  const size_t W0e = Xce + 2654208;
  short* Wp1 = (short*)(ws + W0e);                    // 248,832
  const size_t W1e = W0e + 248832;
  float* Bc0 = (float*)(ws + W1e);                    // 2048
  float* Bc1 = (float*)(ws + W1e + 2048);             // 192
  int* flag = (int*)(ws + W1e + 2048 + 192);          // total ~111.3 MiB

  hipMemsetAsync(ws, 0, zpe, stream);                 // P pair + C0 + C1 + zero page
  detect_dtype<<<1, 64, 0, stream>>>((const unsigned short*)W0, flag);
  canon_x<<<3072, 256, 0, stream>>>(hist, Xc, flag);
  canon_b<<<3, 256, 0, stream>>>(b0, b1, Bc0, Bc1, flag);
  prep_w0<<<(512 * KTOT + 255) / 256, 256, 0, stream>>>(W0, Wp0, flag);
  prep_w1<<<(48 * KTOT + 255) / 256, 256, 0, stream>>>(W1, Wp1, flag);
  fill_x0<<<256, 256, 0, stream>>>(Xc, P[0]);

  for (int t = 0; t <= 12; ++t) {
    fused_step<<<2560, 256, 0, stream>>>(P[t & 1], P[(t + 1) & 1], Wp0, Bc0, C0, Xc,
                                         Wp1, Bc1, C1, d_out, zp, flag, t);
  }
}

// Round 11
// 2201.568 us; speedup vs baseline: 1.9428x; 1.9428x over previous
//
#include <hip/hip_runtime.h>
#include <hip/hip_bf16.h>

// ConvLSTM (2 layers) on MI355X. R11: single-plane FP16 pipeline.
// Packed tensor P (B,64,64,160) fp16: [x(1), h0(128), h1(12), pad(19)].
// bf16 inputs convert to fp16 EXACTLY (x, W exact; only h carries 2^-11 rounding).
// K = 9 taps x 160 = 1440 (was 2592 with hi/lo bf16 split) -> 44% less MFMA work.
// Geometry = R6 (verified best): 256-thr blocks, wave tile 64x64, acc 4x4,
// LDS 33792 dbuf, 1-tap B register prefetch, DMA halo staging.
// gg0 t: P[t&1] -> P[(t+1)&1] (h0,x);  gg1 t: reads P[(t+1)&1], writes h1 -> P[t&1].

typedef __attribute__((ext_vector_type(8))) short short8;
typedef __attribute__((ext_vector_type(4))) float float4v;

#define CS 160
#define KTOT 1440         // 9*160

__device__ __forceinline__ float sigf(float x) { return 1.f / (1.f + __expf(-x)); }
__device__ __forceinline__ short f2hs(float v) {
  _Float16 h = (_Float16)v;
  return *(short*)&h;
}
__device__ __forceinline__ float hs2f(short s) {
  _Float16 h; *(short*)&h = s; return (float)h;
}
__device__ __forceinline__ float bs2f(short s) {
  __hip_bfloat16 h; *(short*)&h = s; return __bfloat162float(h);
}
__device__ __forceinline__ short f2bs(float v) {
  __hip_bfloat16 h = __float2bfloat16(v);
  return *(short*)&h;
}

// async 16B global->LDS; per-lane lds ptr must equal uniform_base + lane*16
__device__ __forceinline__ void async_ld16(const short* g, short* l) {
  __builtin_amdgcn_global_load_lds(
      (const __attribute__((address_space(1))) unsigned int*)g,
      (__attribute__((address_space(3))) unsigned int*)l, 16, 0, 0);
}

// Stage one halo row (66 px x 32 ch) into LDS at dstRow (row-major, 32ch/px).
__device__ __forceinline__ void stage_row(const short* __restrict__ rowPtr, bool rowOK,
                                          short* dstRow, int lane,
                                          const short* __restrict__ zp) {
  #pragma unroll
  for (int j = 0; j < 4; ++j) {
    int e = j * 64 + lane;
    int px = e >> 2, v = e & 3;
    int xx = px - 1;
    const short* g = (rowOK && xx >= 0) ? (rowPtr + (size_t)xx * CS + v * 8) : zp;
    async_ld16(g, dstRow + e * 8);
  }
  if (lane < 8) {
    int px = 64 + (lane >> 2), v = lane & 3, xx = px - 1;
    short8 val = {0, 0, 0, 0, 0, 0, 0, 0};
    if (rowOK && xx < 64) val = *(const short8*)(rowPtr + (size_t)xx * CS + v * 8);
    *(short8*)(dstRow + px * 32 + v * 8) = val;
  }
}

// ---- dtype detect: fp32 low-halves have uniform bits[14:7]; bf16 weights cluster ----
__global__ void detect_dtype(const unsigned short* __restrict__ w0, int* __restrict__ flag) {
  int lane = threadIdx.x;
  int cnt = 0;
  for (int i = 0; i < 4; ++i) {
    unsigned short u = w0[2 * (lane + 64 * i)];
    int e = (u >> 7) & 0xFF;
    unsigned long long b = __ballot(e >= 0xC0);
    cnt += __popcll(b);
  }
  if (lane == 0) *flag = (cnt > 32) ? 1 : 0;   // 1 = fp32 inputs
}

// ---- canonicalize x -> fp16 shorts (bf16->fp16 exact; sanitized) ----
__global__ void canon_x(const void* __restrict__ hist, short* __restrict__ Xc,
                        const int* __restrict__ flag) {
  int i = blockIdx.x * 256 + threadIdx.x;      // < 786432
  float v = (*flag) ? ((const float*)hist)[i] : bs2f(((const short*)hist)[i]);
  if (!isfinite(v) || fabsf(v) > 1e4f) v = 0.f;
  Xc[i] = f2hs(v);
}

__global__ void canon_b(const void* __restrict__ b0, const void* __restrict__ b1,
                        float* __restrict__ Bc0, float* __restrict__ Bc1,
                        const int* __restrict__ flag) {
  int i = blockIdx.x * 256 + threadIdx.x;
  int fl = *flag;
  if (i < 512) {
    float v = fl ? ((const float*)b0)[i] : bs2f(((const short*)b0)[i]);
    if (!isfinite(v) || fabsf(v) > 1e4f) v = 0.f;
    Bc0[i] = v;
  } else if (i < 560) {
    int j = i - 512;
    float v = fl ? ((const float*)b1)[j] : bs2f(((const short*)b1)[j]);
    if (!isfinite(v) || fabsf(v) > 1e4f) v = 0.f;
    Bc1[j] = v;
  }
}

// layer0 W0 (512,129,3,3) -> fp16 Wp[co][tap*160+c]: P-ch 0=x, 1..128=h0, else 0.
__global__ void prep_w0(const void* __restrict__ W0, short* __restrict__ Wp,
                        const int* __restrict__ flag) {
  int i = blockIdx.x * 256 + threadIdx.x;
  if (i >= 512 * KTOT) return;
  int fl = *flag;
  int co = i / KTOT, k = i - co * KTOT;
  int tap = k / CS, c = k - tap * CS;
  int ci = -1;
  if (c == 0) ci = 0;
  else if (c <= 128) ci = c;
  float w = 0.f;
  if (ci >= 0) {
    int widx = (co * 129 + ci) * 9 + tap;
    w = fl ? ((const float*)W0)[widx] : bs2f(((const short*)W0)[widx]);
    if (!isfinite(w) || fabsf(w) > 1e4f) w = 0.f;
  }
  Wp[i] = f2hs(w);
}

// layer1 W1 (48,140,3,3) -> fp16: P-ch 1..128=h0, 129..140=h1, else 0.
__global__ void prep_w1(const void* __restrict__ W1, short* __restrict__ Wp,
                        const int* __restrict__ flag) {
  int i = blockIdx.x * 256 + threadIdx.x;
  if (i >= 48 * KTOT) return;
  int fl = *flag;
  int co = i / KTOT, k = i - co * KTOT;
  int tap = k / CS, c = k - tap * CS;
  int ci = -1;
  if (c >= 1 && c <= 140) ci = c - 1;
  float w = 0.f;
  if (ci >= 0) {
    int widx = (co * 140 + ci) * 9 + tap;
    w = fl ? ((const float*)W1)[widx] : bs2f(((const short*)W1)[widx]);
    if (!isfinite(w) || fabsf(w) > 1e4f) w = 0.f;
  }
  Wp[i] = f2hs(w);
}

__global__ void fill_x0(const short* __restrict__ Xc, short* __restrict__ P0) {
  int p = blockIdx.x * 256 + threadIdx.x;      // b*4096 + pix
  int b = p >> 12, pix = p & 4095;
  P0[(size_t)p * CS] = Xc[b * 12 * 4096 + pix];
}

// ---- layer 0: M=128px (2 rows) x N=128co (4 gates x 32 hc). Grid = 4 nt * 512 mt. ----
__global__ __launch_bounds__(256, 2) void gemm_gate0(
    const short* __restrict__ Pcur, short* __restrict__ Pnext,
    const short* __restrict__ Wp, const float* __restrict__ Bc0,
    float* __restrict__ C0, const short* __restrict__ Xc,
    const short* __restrict__ zp, int t) {
  int bx = blockIdx.x;
  int nt = bx >> 9, mt = bx & 511;             // consecutive blocks share nt (weight L2 reuse)
  int b = mt >> 5, y0 = (mt & 31) * 2;
  int tid = threadIdx.x, wave = tid >> 6, lane = tid & 63;
  int ln15 = lane & 15, quad = lane >> 4;
  int wm = wave & 1, wn = wave >> 1;
  int hc = nt * 32 + wn * 16 + ln15;

  __shared__ __align__(16) short halo[2 * 4 * 66 * 32];   // dbuf, 33792 B

  float4v acc[4][4];
  #pragma unroll
  for (int i = 0; i < 4; ++i)
    #pragma unroll
    for (int j = 0; j < 4; ++j) acc[i][j] = (float4v){0.f, 0.f, 0.f, 0.f};

  // B frag addr (g, tap, c0): wbase + g*128*KTOT + tap*CS + c0
  const short* wbase = Wp + (size_t)hc * KTOT + quad * 8;
  short8 bcur[4], bnxt[4];
  #pragma unroll
  for (int g = 0; g < 4; ++g)
    bcur[g] = *(const short8*)(wbase + (size_t)g * 128 * KTOT);

  int yy = y0 - 1 + wave;
  bool rowOK = (yy >= 0) && (yy < 64);
  const short* rowBase = Pcur + (size_t)((b * 64 + yy) * 64) * CS;

  stage_row(rowBase, rowOK, halo + wave * 2112, lane, zp);
  __syncthreads();

  for (int ch = 0; ch < 5; ++ch) {
    int c0 = ch * 32;
    const short* cur = halo + (ch & 1) * 8448;
    if (ch < 4)
      stage_row(rowBase + c0 + 32, rowOK, halo + ((ch + 1) & 1) * 8448 + wave * 2112,
                lane, zp);
    #pragma unroll
    for (int tap = 0; tap < 9; ++tap) {
      int dy = tap / 3, dx = tap - dy * 3;
      // prefetch next tap's (or next chunk's tap-0) B fragments
      int ntap = (tap < 8) ? tap + 1 : 0;
      int nc0 = (tap < 8) ? c0 : ((ch < 4) ? c0 + 32 : c0);
      #pragma unroll
      for (int g = 0; g < 4; ++g)
        bnxt[g] = *(const short8*)(wbase + (size_t)g * 128 * KTOT + ntap * CS + nc0);

      short8 af[4];
      #pragma unroll
      for (int mf = 0; mf < 4; ++mf)
        af[mf] = *(const short8*)&cur[((wm + dy) * 66 + mf * 16 + ln15 + dx) * 32 + quad * 8];
      #pragma unroll
      for (int g = 0; g < 4; ++g)
        #pragma unroll
        for (int mf = 0; mf < 4; ++mf)
          acc[mf][g] = __builtin_amdgcn_mfma_f32_16x16x32_f16(af[mf], bcur[g], acc[mf][g], 0, 0, 0);
      #pragma unroll
      for (int g = 0; g < 4; ++g) bcur[g] = bnxt[g];
    }
    __syncthreads();
  }

  // epilogue: all 4 gates in-register per (pix,hc)
  float bi = Bc0[hc], bff = Bc0[128 + hc], bo = Bc0[256 + hc], bg = Bc0[384 + hc];
  int rowPix = (b * 64 + y0 + wm) * 64;
  #pragma unroll
  for (int mf = 0; mf < 4; ++mf) {
    #pragma unroll
    for (int r = 0; r < 4; ++r) {
      int x = mf * 16 + quad * 4 + r;          // C/D row = quad*4 + reg
      int pix = rowPix + x;
      float zi = acc[mf][0][r] + bi;
      float zf = acc[mf][1][r] + bff;
      float zo = acc[mf][2][r] + bo;
      float zg = acc[mf][3][r] + bg;
      float cprev = C0[(size_t)pix * 128 + hc];
      float cn = sigf(zf) * cprev + sigf(zi) * tanhf(zg);
      float hn = sigf(zo) * tanhf(cn);
      C0[(size_t)pix * 128 + hc] = cn;
      Pnext[(size_t)pix * CS + 1 + hc] = f2hs(hn);
    }
  }
  if (nt == 0 && t < 11 && tid < 128) {
    int rr = tid >> 6, x = tid & 63;
    int yw = y0 + rr;
    Pnext[(size_t)((b * 64 + yw) * 64 + x) * CS] = Xc[(b * 12 + t + 1) * 4096 + yw * 64 + x];
  }
}

// ---- layer 1: M=128px (2 rows) x N=48co. Grid 512. B register-prefetch. ----
__global__ __launch_bounds__(256, 2) void gemm_gate1(
    const short* __restrict__ Prd, short* __restrict__ Pwr,
    const short* __restrict__ Wp, const float* __restrict__ Bc1,
    float* __restrict__ C1, void* __restrict__ outp,
    const short* __restrict__ zp, const int* __restrict__ flagp, int t) {
  int bid = blockIdx.x;                        // 0..511
  int b = bid >> 5, y0 = (bid & 31) * 2;
  int tid = threadIdx.x, wave = tid >> 6, lane = tid & 63;
  int ln15 = lane & 15, quad = lane >> 4;
  int wr = wave >> 1, wh = wave & 1;
  int flagv = *flagp;

  __shared__ __align__(16) short halo[2 * 4 * 66 * 32];   // 33792 B

  float4v acc[2][3];
  #pragma unroll
  for (int i = 0; i < 2; ++i)
    #pragma unroll
    for (int j = 0; j < 3; ++j) acc[i][j] = (float4v){0.f, 0.f, 0.f, 0.f};

  int yy = y0 - 1 + wave;
  bool rowOK = (yy >= 0) && (yy < 64);
  const short* rowBase = Prd + (size_t)((b * 64 + yy) * 64) * CS;

  const short* wbase = Wp + (size_t)ln15 * KTOT + quad * 8;
  short8 bcur[3], bnxt[3];
  #pragma unroll
  for (int nf = 0; nf < 3; ++nf)
    bcur[nf] = *(const short8*)(wbase + (size_t)nf * 16 * KTOT);

  stage_row(rowBase, rowOK, halo + wave * 2112, lane, zp);
  __syncthreads();

  for (int ch = 0; ch < 5; ++ch) {
    int c0 = ch * 32;
    const short* cur = halo + (ch & 1) * 8448;
    if (ch < 4)
      stage_row(rowBase + c0 + 32, rowOK, halo + ((ch + 1) & 1) * 8448 + wave * 2112,
                lane, zp);
    #pragma unroll
    for (int tap = 0; tap < 9; ++tap) {
      int dy = tap / 3, dx = tap - dy * 3;
      int ntap = (tap < 8) ? tap + 1 : 0;
      int nc0 = (tap < 8) ? c0 : ((ch < 4) ? c0 + 32 : c0);
      #pragma unroll
      for (int nf = 0; nf < 3; ++nf)
        bnxt[nf] = *(const short8*)(wbase + (size_t)nf * 16 * KTOT + ntap * CS + nc0);

      short8 af[2];
      #pragma unroll
      for (int mf = 0; mf < 2; ++mf)
        af[mf] = *(const short8*)&cur[((wr + dy) * 66 + wh * 32 + mf * 16 + ln15 + dx) * 32
                                      + quad * 8];
      #pragma unroll
      for (int nf = 0; nf < 3; ++nf)
        #pragma unroll
        for (int mf = 0; mf < 2; ++mf)
          acc[mf][nf] = __builtin_amdgcn_mfma_f32_16x16x32_f16(af[mf], bcur[nf], acc[mf][nf], 0, 0, 0);
      #pragma unroll
      for (int nf = 0; nf < 3; ++nf) bcur[nf] = bnxt[nf];
    }
    __syncthreads();
  }

  // z -> LDS (reuse halo: 128*48 fp32 = 24576 B), then gate pass
  float* zbuf = (float*)halo;
  #pragma unroll
  for (int mf = 0; mf < 2; ++mf)
    #pragma unroll
    for (int nf = 0; nf < 3; ++nf)
      #pragma unroll
      for (int r = 0; r < 4; ++r) {
        int pxl = wr * 64 + wh * 32 + mf * 16 + quad * 4 + r;
        zbuf[pxl * 48 + nf * 16 + ln15] = acc[mf][nf][r];
      }
  __syncthreads();

  #pragma unroll
  for (int k = 0; k < 6; ++k) {
    int id = k * 256 + tid;
    int hc = id >> 7, pxl = id & 127;
    float zi = zbuf[pxl * 48 + hc]      + Bc1[hc];
    float zf = zbuf[pxl * 48 + 12 + hc] + Bc1[12 + hc];
    float zo = zbuf[pxl * 48 + 24 + hc] + Bc1[24 + hc];
    float zg = zbuf[pxl * 48 + 36 + hc] + Bc1[36 + hc];
    int y = y0 + (pxl >> 6), x = pxl & 63;
    int pix = (b * 64 + y) * 64 + x;
    float cprev = C1[(size_t)pix * 12 + hc];
    float cn = sigf(zf) * cprev + sigf(zi) * tanhf(zg);
    float hn = sigf(zo) * tanhf(cn);
    C1[(size_t)pix * 12 + hc] = cn;
    Pwr[(size_t)pix * CS + 129 + hc] = f2hs(hn);
    if (t == 11) {
      int oidx = (b * 12 + hc) * 4096 + y * 64 + x;
      if (flagv) ((float*)outp)[oidx] = hn;
      else ((short*)outp)[oidx] = f2bs(hn);
    }
  }
}

extern "C" void kernel_launch(void* const* d_in, const int* in_sizes, int n_in,
                              void* d_out, int out_size, void* d_ws, size_t ws_size,
                              hipStream_t stream) {
  const void* hist = d_in[0];                  // (16,12,4096,1)
  const void* W0 = d_in[2];                    // (512,129,3,3)
  const void* b0 = d_in[3];
  const void* W1 = d_in[4];                    // (48,140,3,3)
  const void* b1 = d_in[5];

  char* ws = (char*)d_ws;
  const size_t PszB = (size_t)16 * 4096 * CS * 2;     // 20,971,520
  short* P[2] = {(short*)ws, (short*)(ws + PszB)};
  float* C0 = (float*)(ws + 2 * PszB);                // 33,554,432
  const size_t C0e = 2 * PszB + 33554432;
  float* C1 = (float*)(ws + C0e);                     // 3,145,728
  const size_t C1e = C0e + 3145728;
  short* zp = (short*)(ws + C1e);                     // 256 B zero page
  const size_t zpe = C1e + 256;
  short* Xc = (short*)(ws + zpe);                     // 1,572,864
  const size_t Xce = zpe + 1572864;
  short* Wp0 = (short*)(ws + Xce);                    // 512*1440*2 = 1,474,560
  const size_t W0e = Xce + (size_t)512 * KTOT * 2;
  short* Wp1 = (short*)(ws + W0e);                    // 48*1440*2 = 138,240
  const size_t W1e = W0e + (size_t)48 * KTOT * 2;
  float* Bc0 = (float*)(ws + W1e);                    // 2048
  float* Bc1 = (float*)(ws + W1e + 2048);             // 192
  int* flag = (int*)(ws + W1e + 2048 + 192);          // total ~82 MiB

  hipMemsetAsync(ws, 0, zpe, stream);                 // P pair + C0 + C1 + zero page
  detect_dtype<<<1, 64, 0, stream>>>((const unsigned short*)W0, flag);
  canon_x<<<3072, 256, 0, stream>>>(hist, Xc, flag);
  canon_b<<<3, 256, 0, stream>>>(b0, b1, Bc0, Bc1, flag);
  prep_w0<<<(512 * KTOT + 255) / 256, 256, 0, stream>>>(W0, Wp0, flag);
  prep_w1<<<(48 * KTOT + 255) / 256, 256, 0, stream>>>(W1, Wp1, flag);
  fill_x0<<<256, 256, 0, stream>>>(Xc, P[0]);

  for (int t = 0; t < 12; ++t) {
    gemm_gate0<<<2048, 256, 0, stream>>>(P[t & 1], P[(t + 1) & 1], Wp0, Bc0, C0, Xc, zp, t);
    gemm_gate1<<<512, 256, 0, stream>>>(P[(t + 1) & 1], P[t & 1], Wp1, Bc1, C1,
                                        d_out, zp, flag, t);
  }
}